// Round 9
// baseline (693.188 us; speedup 1.0000x reference)
//
#include <hip/hip_runtime.h>
#include <hip/hip_bf16.h>

#define N_NODES 100000
#define N_EDGES 3200000
#define CH 128
#define NG 128
#define BN_EPS 1e-5f
#define NBUCK 1024   // bucket = dst >> 7 (128 nodes per bucket)
#define EPB 16384    // edges per k_bin block

__device__ __forceinline__ unsigned int packq(const float* v, float inv) {
    int q0 = __float2int_rn(v[0] * inv), q1 = __float2int_rn(v[1] * inv);
    int q2 = __float2int_rn(v[2] * inv), q3 = __float2int_rn(v[3] * inv);
    return (unsigned int)(q0 & 255) | ((unsigned int)(q1 & 255) << 8) |
           ((unsigned int)(q2 & 255) << 16) | ((unsigned int)(q3 & 255) << 24);
}

__device__ __forceinline__ void acc4(float f, unsigned int a, float* acc) {
    acc[0] += f * (float)(((int)a << 24) >> 24);
    acc[1] += f * (float)(((int)a << 16) >> 24);
    acc[2] += f * (float)(((int)a << 8) >> 24);
    acc[3] += f * (float)((int)a >> 24);
}
__device__ __forceinline__ void acc16f(float f, uint4 v, float* acc) {
    acc4(f, v.x, acc); acc4(f, v.y, acc + 4); acc4(f, v.z, acc + 8); acc4(f, v.w, acc + 12);
}

// ---------------- bucket histogram ----------------
__global__ __launch_bounds__(256) void k_bhist(const int* __restrict__ dst, int* __restrict__ bcnt) {
    __shared__ int lh[NBUCK];
    for (int i = threadIdx.x; i < NBUCK; i += 256) lh[i] = 0;
    __syncthreads();
    for (int e = blockIdx.x * 256 + threadIdx.x; e < N_EDGES; e += gridDim.x * 256)
        atomicAdd(&lh[dst[e] >> 7], 1);
    __syncthreads();
    for (int i = threadIdx.x; i < NBUCK; i += 256) {
        int v = lh[i];
        if (v) atomicAdd(&bcnt[i], v);
    }
}

// ---------------- scan 1024 -> exclusive bases (+ optional cursor copy) ----------------
__global__ __launch_bounds__(256) void k_bscan(const int* __restrict__ in, int* __restrict__ out,
                                               int* __restrict__ cur) {
    __shared__ int sm[256];
    int t = threadIdx.x;
    int4 v = *(const int4*)&in[t * 4];
    int tsum = v.x + v.y + v.z + v.w;
    sm[t] = tsum;
    __syncthreads();
    for (int off = 1; off < 256; off <<= 1) {
        int val = sm[t];
        int add = (t >= off) ? sm[t - off] : 0;
        __syncthreads();
        sm[t] = val + add;
        __syncthreads();
    }
    int excl = sm[t] - tsum;
    int o0 = excl, o1 = excl + v.x, o2 = o1 + v.y, o3 = o2 + v.z;
    out[t * 4] = o0; out[t * 4 + 1] = o1; out[t * 4 + 2] = o2; out[t * 4 + 3] = o3;
    if (cur) { cur[t * 4] = o0; cur[t * 4 + 1] = o1; cur[t * 4 + 2] = o2; cur[t * 4 + 3] = o3; }
}

// ---------------- bin edges into per-bucket packed segments ----------------
__global__ __launch_bounds__(256) void k_bin(const int* __restrict__ src, const int* __restrict__ dst,
                                             int* __restrict__ bcur, unsigned int* __restrict__ pairs) {
    __shared__ int lhist[NBUCK];
    __shared__ int lbase[NBUCK];
    int t = threadIdx.x;
    for (int i = t; i < NBUCK; i += 256) lhist[i] = 0;
    __syncthreads();
    int base = blockIdx.x * EPB;
    int lim = min(base + EPB, N_EDGES);
    for (int e = base + t; e < lim; e += 256)
        atomicAdd(&lhist[dst[e] >> 7], 1);
    __syncthreads();
    for (int i = t; i < NBUCK; i += 256) {
        int h = lhist[i];
        lbase[i] = h ? atomicAdd(&bcur[i], h) : 0;
        lhist[i] = 0;
    }
    __syncthreads();
    for (int e = base + t; e < lim; e += 256) {
        int d = dst[e];
        int b = d >> 7;
        int r = atomicAdd(&lhist[b], 1);
        pairs[lbase[b] + r] = ((unsigned int)src[e] << 7) | ((unsigned int)d & 127u);
    }
}

// ---------------- pass A: per-bucket padded totals + dinv ----------------
__global__ __launch_bounds__(256) void k_bfillA(const unsigned int* __restrict__ pairs,
                                                const int* __restrict__ boffs,
                                                int* __restrict__ PT, float* __restrict__ dinv) {
    __shared__ int cnt[128];
    __shared__ int sm[128];
    int b = blockIdx.x, t = threadIdx.x;
    if (t < 128) cnt[t] = 0;
    __syncthreads();
    int p0 = boffs[b];
    int p1 = (b == NBUCK - 1) ? N_EDGES : boffs[b + 1];
    for (int p = p0 + t; p < p1; p += 256) atomicAdd(&cnt[pairs[p] & 127u], 1);
    __syncthreads();
    if (t < 128) {
        int node = (b << 7) + t;
        int L = 0;
        if (node < N_NODES) {
            int d = cnt[t];
            dinv[node] = rsqrtf((float)(d + 1));
            L = (d + 32) & ~31;   // room for deg + self + padding, multiple of 32
        }
        sm[t] = L;
    }
    __syncthreads();
    for (int off = 64; off > 0; off >>= 1) {
        if (t < off) sm[t] += sm[t + off];
        __syncthreads();
    }
    if (t == 0) PT[b] = sm[0];
}

// ---------------- pass C: padded CSR fill; pad = [self, dummy...] ----------------
__global__ __launch_bounds__(256) void k_bfillC(const unsigned int* __restrict__ pairs,
                                                const int* __restrict__ boffs,
                                                const int* __restrict__ PB,
                                                int* __restrict__ offs, int* __restrict__ perm) {
    __shared__ int cnt[128], lsc[128], lpos[128];
    int b = blockIdx.x, t = threadIdx.x;
    if (t < 128) cnt[t] = 0;
    __syncthreads();
    int p0 = boffs[b];
    int p1 = (b == NBUCK - 1) ? N_EDGES : boffs[b + 1];
    for (int p = p0 + t; p < p1; p += 256) atomicAdd(&cnt[pairs[p] & 127u], 1);
    __syncthreads();
    int L = 0;
    if (t < 128) {
        int node = (b << 7) + t;
        if (node < N_NODES) L = (cnt[t] + 32) & ~31;
        lsc[t] = L;
    }
    __syncthreads();
    for (int off = 1; off < 128; off <<= 1) {
        int val = 0, add = 0;
        if (t < 128) { val = lsc[t]; add = (t >= off) ? lsc[t - off] : 0; }
        __syncthreads();
        if (t < 128) lsc[t] = val + add;
        __syncthreads();
    }
    if (t < 128) {
        int node = (b << 7) + t;
        int base = PB[b] + lsc[t] - L;
        lpos[t] = base;
        if (node < N_NODES) {
            offs[node] = base;
            if (node == N_NODES - 1) offs[N_NODES] = base + L;
        }
        cnt[t] = 0;
    }
    __syncthreads();
    for (int p = p0 + t; p < p1; p += 256) {
        unsigned int e = pairs[p];
        int l = (int)(e & 127u);
        int r = atomicAdd(&cnt[l], 1);
        perm[lpos[l] + r] = (int)(e >> 7);
    }
    __syncthreads();
    if (t < 128) {
        int node = (b << 7) + t;
        if (node < N_NODES) {
            int d = cnt[t], base = lpos[t];
            perm[base + d] = node;              // self-loop edge (coef di*spre[node])
            int Lr = (d + 32) & ~31;
            for (int k = d + 1; k < Lr; ++k) perm[base + k] = N_NODES;  // dummy zero row
        }
    }
}

// ---------------- fold BN into per-channel A/B ----------------
__global__ void k_prep(const float* __restrict__ gamma, const float* __restrict__ beta,
                       const float* __restrict__ rmean, const float* __restrict__ rvar,
                       const float* __restrict__ b1, float* __restrict__ A1, float* __restrict__ B1) {
    int c = threadIdx.x;
    float a = gamma[c] * rsqrtf(rvar[c] + BN_EPS);
    A1[c] = a;
    B1[c] = (b1[c] - rmean[c]) * a + beta[c];
}

// ---------------- zero the dummy row + dummy scales ----------------
__global__ void k_zpad(uint4* __restrict__ bufA, uint4* __restrict__ bufC,
                       float* __restrict__ spreA, float* __restrict__ spreC) {
    int t = threadIdx.x;
    if (t < 8) {
        bufA[(size_t)N_NODES * 8 + t] = make_uint4(0, 0, 0, 0);
        bufC[(size_t)N_NODES * 8 + t] = make_uint4(0, 0, 0, 0);
    }
    if (t == 8) spreA[N_NODES] = 0.f;
    if (t == 9) spreC[N_NODES] = 0.f;
}

// ---------------- GEMM: int8 out with row-max quant; MODE 0 fp32 in, MODE 2 int8 in ----------------
template <int MODE>
__global__ __launch_bounds__(256) void k_gemm(const void* __restrict__ Xv, const float* __restrict__ xsc,
                                              const float* __restrict__ W, const float* __restrict__ dinvp,
                                              uint2* __restrict__ Yq, float* __restrict__ ospre, int nrows) {
    __shared__ float xsT[128 * 64];  // [k][r]
    int row0 = blockIdx.x * 64;
    int t = threadIdx.x;
    {
        int r = t >> 2, q = t & 3;
        int grow = row0 + r;
        bool ok = grow < nrows;
        if (MODE == 2) {
            float sc = ok ? xsc[grow] : 0.f;
            const uint2* srcp = (const uint2*)Xv + (size_t)grow * 16 + q * 4;
            #pragma unroll
            for (int i = 0; i < 4; ++i) {
                uint2 u = ok ? srcp[i] : make_uint2(0, 0);
                int a = (int)u.x, bb = (int)u.y;
                int c = q * 32 + i * 8;
                xsT[(c + 0) * 64 + r] = sc * (float)((a << 24) >> 24);
                xsT[(c + 1) * 64 + r] = sc * (float)((a << 16) >> 24);
                xsT[(c + 2) * 64 + r] = sc * (float)((a << 8) >> 24);
                xsT[(c + 3) * 64 + r] = sc * (float)(a >> 24);
                xsT[(c + 4) * 64 + r] = sc * (float)((bb << 24) >> 24);
                xsT[(c + 5) * 64 + r] = sc * (float)((bb << 16) >> 24);
                xsT[(c + 6) * 64 + r] = sc * (float)((bb << 8) >> 24);
                xsT[(c + 7) * 64 + r] = sc * (float)(bb >> 24);
            }
        } else {
            const float4* srcp = (const float4*)((const float*)Xv + (size_t)grow * CH + q * 32);
            #pragma unroll
            for (int i = 0; i < 8; ++i) {
                float4 v = ok ? srcp[i] : make_float4(0.f, 0.f, 0.f, 0.f);
                int c = q * 32 + i * 4;
                xsT[(c + 0) * 64 + r] = v.x;
                xsT[(c + 1) * 64 + r] = v.y;
                xsT[(c + 2) * 64 + r] = v.z;
                xsT[(c + 3) * 64 + r] = v.w;
            }
        }
    }
    __syncthreads();
    int tx = t & 15, ty = t >> 4;
    float acc[4][8];
    #pragma unroll
    for (int i = 0; i < 4; ++i)
        #pragma unroll
        for (int j = 0; j < 8; ++j) acc[i][j] = 0.f;

    const float4* xs4 = (const float4*)xsT;
    #pragma unroll 4
    for (int k = 0; k < 128; ++k) {
        float4 a = xs4[k * 16 + ty];
        float4 w0 = *(const float4*)&W[k * CH + tx * 8];
        float4 w1 = *(const float4*)&W[k * CH + tx * 8 + 4];
        float av[4] = {a.x, a.y, a.z, a.w};
        float wv[8] = {w0.x, w0.y, w0.z, w0.w, w1.x, w1.y, w1.z, w1.w};
        #pragma unroll
        for (int i = 0; i < 4; ++i)
            #pragma unroll
            for (int j = 0; j < 8; ++j) acc[i][j] += av[i] * wv[j];
    }
    #pragma unroll
    for (int i = 0; i < 4; ++i) {
        int grow = row0 + ty * 4 + i;
        float m = 0.f;
        #pragma unroll
        for (int j = 0; j < 8; ++j) m = fmaxf(m, fabsf(acc[i][j]));
        #pragma unroll
        for (int off = 1; off < 16; off <<= 1) m = fmaxf(m, __shfl_xor(m, off, 64));
        float inv = (m > 0.f) ? 127.0f / m : 0.f;
        if (grow < nrows) {
            uint2 pk;
            pk.x = packq(&acc[i][0], inv);
            pk.y = packq(&acc[i][4], inv);
            Yq[(size_t)grow * 16 + tx] = pk;
            if (tx == 0) ospre[grow] = (m * (1.0f / 127.0f)) * dinvp[grow];
        }
    }
}

// ---------------- SpMM gather: 8 slots x 8 lanes, int4 perm, uint4 rows ----------------
// per 32 edges: 1 perm + 4 spre + 4 row-gather vmem instructions.
#define SPMM_GATHER16()                                                \
    int w = threadIdx.x >> 6;                                          \
    int row = __builtin_amdgcn_readfirstlane(blockIdx.x * 4 + w);      \
    int lane = threadIdx.x & 63;                                       \
    int slot = lane >> 3, sub = lane & 7;                              \
    float di = dinv[row];                                              \
    int beg = offs[row], end = offs[row + 1];                          \
    float acc[16];                                                     \
    _Pragma("unroll") for (int i = 0; i < 16; ++i) acc[i] = 0.f;       \
    for (int j = beg; j < end; j += 32) {                              \
        int4 idx = *(const int4*)&perm[j + slot * 4];                  \
        float f0 = spre[idx.x], f1 = spre[idx.y];                      \
        float f2 = spre[idx.z], f3 = spre[idx.w];                      \
        uint4 v0 = xq[(size_t)idx.x * 8 + sub];                        \
        uint4 v1 = xq[(size_t)idx.y * 8 + sub];                        \
        uint4 v2 = xq[(size_t)idx.z * 8 + sub];                        \
        uint4 v3 = xq[(size_t)idx.w * 8 + sub];                        \
        acc16f(di * f0, v0, acc); acc16f(di * f1, v1, acc);            \
        acc16f(di * f2, v2, acc); acc16f(di * f3, v3, acc);            \
    }                                                                  \
    _Pragma("unroll") for (int i = 0; i < 16; ++i) {                   \
        acc[i] += __shfl_xor(acc[i], 8, 64);                           \
        acc[i] += __shfl_xor(acc[i], 16, 64);                          \
        acc[i] += __shfl_xor(acc[i], 32, 64);                          \
    }

// ---------------- SpMM layer 1: + BN(ReLU) -> int8 + raw scale ----------------
__global__ __launch_bounds__(256) void k_spmm1(
    const uint4* __restrict__ xq, const int* __restrict__ perm, const int* __restrict__ offs,
    const float* __restrict__ dinv, const float* __restrict__ spre,
    const float* __restrict__ A1, const float* __restrict__ B1,
    uint4* __restrict__ outq, float* __restrict__ osraw) {
    SPMM_GATHER16()
    int ch0 = sub * 16;
    const float4* A4 = (const float4*)&A1[ch0];
    const float4* B4 = (const float4*)&B1[ch0];
    float r[16];
    #pragma unroll
    for (int q = 0; q < 4; ++q) {
        float4 aa = A4[q], bb = B4[q];
        r[q * 4 + 0] = fmaxf(acc[q * 4 + 0] * aa.x + bb.x, 0.f);
        r[q * 4 + 1] = fmaxf(acc[q * 4 + 1] * aa.y + bb.y, 0.f);
        r[q * 4 + 2] = fmaxf(acc[q * 4 + 2] * aa.z + bb.z, 0.f);
        r[q * 4 + 3] = fmaxf(acc[q * 4 + 3] * aa.w + bb.w, 0.f);
    }
    float m = 0.f;
    #pragma unroll
    for (int i = 0; i < 16; ++i) m = fmaxf(m, r[i]);
    m = fmaxf(m, __shfl_xor(m, 1, 64));
    m = fmaxf(m, __shfl_xor(m, 2, 64));
    m = fmaxf(m, __shfl_xor(m, 4, 64));
    float inv = (m > 0.f) ? 127.0f / m : 0.f;
    uint4 pk;
    pk.x = packq(&r[0], inv); pk.y = packq(&r[4], inv);
    pk.z = packq(&r[8], inv); pk.w = packq(&r[12], inv);
    if (lane < 8) outq[(size_t)row * 8 + sub] = pk;
    if (lane == 0) osraw[row] = m * (1.0f / 127.0f);
}

// ---------------- SpMM layer 2: + bias + pooled-sum (block-reduced atomics) ----------------
__global__ __launch_bounds__(256) void k_spmm_pool(
    const uint4* __restrict__ xq, const int* __restrict__ perm, const int* __restrict__ offs,
    const float* __restrict__ dinv, const float* __restrict__ spre, const float* __restrict__ bias,
    const int* __restrict__ batch, float* __restrict__ psum, int* __restrict__ pcnt) {
    __shared__ float red[4][128];
    __shared__ int gid[4];
    SPMM_GATHER16()
    if (lane < 8) {
        int ch0 = sub * 16;
        const float4* Bb = (const float4*)&bias[ch0];
        #pragma unroll
        for (int q = 0; q < 4; ++q) {
            float4 bb = Bb[q];
            red[w][ch0 + q * 4 + 0] = acc[q * 4 + 0] + bb.x;
            red[w][ch0 + q * 4 + 1] = acc[q * 4 + 1] + bb.y;
            red[w][ch0 + q * 4 + 2] = acc[q * 4 + 2] + bb.z;
            red[w][ch0 + q * 4 + 3] = acc[q * 4 + 3] + bb.w;
        }
    }
    if (lane == 0) gid[w] = batch[row];
    __syncthreads();
    bool same = (gid[0] == gid[1]) && (gid[1] == gid[2]) && (gid[2] == gid[3]);
    int c0 = lane * 2;
    if (same) {
        if (w == 0) {
            float sx = red[0][c0] + red[1][c0] + red[2][c0] + red[3][c0];
            float sy = red[0][c0 + 1] + red[1][c0 + 1] + red[2][c0 + 1] + red[3][c0 + 1];
            unsafeAtomicAdd(&psum[gid[0] * CH + c0], sx);
            unsafeAtomicAdd(&psum[gid[0] * CH + c0 + 1], sy);
            if (lane == 0) atomicAdd(&pcnt[gid[0]], 4);
        }
    } else {
        unsafeAtomicAdd(&psum[gid[w] * CH + c0], red[w][c0]);
        unsafeAtomicAdd(&psum[gid[w] * CH + c0 + 1], red[w][c0 + 1]);
        if (lane == 0) atomicAdd(&pcnt[gid[w]], 1);
    }
}

// ---------------- head ----------------
__global__ __launch_bounds__(128) void k_head(const float* __restrict__ psum, const int* __restrict__ pcnt,
                                              const float* __restrict__ fw1, const float* __restrict__ fb1,
                                              const float* __restrict__ cw, const float* __restrict__ cb,
                                              float* __restrict__ out) {
    __shared__ float fws[128 * 64];
    for (int i = threadIdx.x; i < 128 * 64; i += 128) fws[i] = fw1[i];
    __syncthreads();
    int g = threadIdx.x;
    float z[64];
    #pragma unroll
    for (int j = 0; j < 64; ++j) z[j] = fb1[j];
    float cnt = fmaxf((float)pcnt[g], 1.f);
    float inv = 1.f / cnt;
    for (int c = 0; c < 128; ++c) {
        float p = psum[g * CH + c] * inv;
        #pragma unroll
        for (int j = 0; j < 64; ++j) z[j] += p * fws[c * 64 + j];
    }
    float o0 = cb[0], o1 = cb[1];
    #pragma unroll
    for (int j = 0; j < 64; ++j) {
        float zz = fmaxf(z[j], 0.f);
        o0 += zz * cw[j * 2];
        o1 += zz * cw[j * 2 + 1];
    }
    out[g * 2] = o0;
    out[g * 2 + 1] = o1;
}

extern "C" void kernel_launch(void* const* d_in, const int* in_sizes, int n_in,
                              void* d_out, int out_size, void* d_ws, size_t ws_size,
                              hipStream_t stream) {
    const float* x     = (const float*)d_in[0];
    const int*   ei    = (const int*)d_in[1];
    const int*   batch = (const int*)d_in[2];
    const float* W1    = (const float*)d_in[3];
    const float* b1    = (const float*)d_in[4];
    const float* gamma = (const float*)d_in[5];
    const float* beta  = (const float*)d_in[6];
    const float* rmean = (const float*)d_in[7];
    const float* rvar  = (const float*)d_in[8];
    const float* W2    = (const float*)d_in[9];
    const float* b2    = (const float*)d_in[10];
    const float* fw1   = (const float*)d_in[11];
    const float* fb1   = (const float*)d_in[12];
    const float* cw    = (const float*)d_in[13];
    const float* cb    = (const float*)d_in[14];
    const int* srcp = ei;
    const int* dstp = ei + N_EDGES;

    char* w = (char*)d_ws;
    // zeroed region first
    int*   bcnt  = (int*)w;   w += 4096;
    float* psum  = (float*)w; w += 65536;
    int*   pcnt  = (int*)w;   w += 512;
    size_t zbytes = 4096 + 65536 + 512;
    // non-zeroed
    int*   boffs = (int*)w;   w += 4096;
    int*   bcur  = (int*)w;   w += 4096;
    int*   PT    = (int*)w;   w += 4096;
    int*   PB    = (int*)w;   w += 4096;
    float* A1    = (float*)w; w += 512;
    float* B1    = (float*)w; w += 512;
    int*   offs  = (int*)w;   w += 400016;   // N+1 ints (padded)
    float* dinv  = (float*)w; w += 400016;
    float* spreA = (float*)w; w += 400016;   // N+1 (dummy = 0)
    float* srawB = (float*)w; w += 400000;
    float* spreC = (float*)w; w += 400016;   // N+1 (dummy = 0)
    unsigned int* pairs = (unsigned int*)w; w += 12800000;   // 3.2M
    int*   perm  = (int*)w;   w += 26000000;                 // padded CSR, <= 6.5M
    uint2* bufA  = (uint2*)w; w += 12812928;  // int8 [100k+1,128]
    uint2* bufB  = (uint2*)w; w += 12800000;  // int8 [100k,128]
    uint2* bufC  = (uint2*)w; w += 12812928;  // int8 [100k+1,128]

    hipMemsetAsync(d_ws, 0, zbytes, stream);
    k_bhist<<<200, 256, 0, stream>>>(dstp, bcnt);
    k_bscan<<<1, 256, 0, stream>>>(bcnt, boffs, bcur);
    k_bin<<<(N_EDGES + EPB - 1) / EPB, 256, 0, stream>>>(srcp, dstp, bcur, pairs);
    k_bfillA<<<NBUCK, 256, 0, stream>>>(pairs, boffs, PT, dinv);
    k_bscan<<<1, 256, 0, stream>>>(PT, PB, nullptr);
    k_bfillC<<<NBUCK, 256, 0, stream>>>(pairs, boffs, PB, offs, perm);
    k_zpad<<<1, 64, 0, stream>>>((uint4*)bufA, (uint4*)bufC, spreA, spreC);
    k_prep<<<1, 128, 0, stream>>>(gamma, beta, rmean, rvar, b1, A1, B1);
    k_gemm<0><<<1563, 256, 0, stream>>>(x, nullptr, W1, dinv, bufA, spreA, N_NODES);
    k_spmm1<<<25000, 256, 0, stream>>>((const uint4*)bufA, perm, offs, dinv, spreA,
                                       A1, B1, (uint4*)bufB, srawB);
    k_gemm<2><<<1563, 256, 0, stream>>>(bufB, srawB, W2, dinv, bufC, spreC, N_NODES);
    k_spmm_pool<<<25000, 256, 0, stream>>>((const uint4*)bufC, perm, offs, dinv, spreC,
                                           b2, batch, psum, pcnt);
    k_head<<<1, 128, 0, stream>>>(psum, pcnt, fw1, fb1, cw, cb, (float*)d_out);
}

// Round 10
// 645.194 us; speedup vs baseline: 1.0744x; 1.0744x over previous
//
#include <hip/hip_runtime.h>
#include <hip/hip_bf16.h>

#define N_NODES 100000
#define N_EDGES 3200000
#define CH 128
#define NG 128
#define BN_EPS 1e-5f
#define NBUCK 1024   // bucket = dst >> 7 (128 nodes per bucket)
#define EPB 16384    // edges per k_bin block

__device__ __forceinline__ unsigned int packq(const float* v, float inv) {
    int q0 = __float2int_rn(v[0] * inv), q1 = __float2int_rn(v[1] * inv);
    int q2 = __float2int_rn(v[2] * inv), q3 = __float2int_rn(v[3] * inv);
    return (unsigned int)(q0 & 255) | ((unsigned int)(q1 & 255) << 8) |
           ((unsigned int)(q2 & 255) << 16) | ((unsigned int)(q3 & 255) << 24);
}

// ---------------- bucket histogram ----------------
__global__ __launch_bounds__(256) void k_bhist(const int* __restrict__ dst, int* __restrict__ bcnt) {
    __shared__ int lh[NBUCK];
    for (int i = threadIdx.x; i < NBUCK; i += 256) lh[i] = 0;
    __syncthreads();
    for (int e = blockIdx.x * 256 + threadIdx.x; e < N_EDGES; e += gridDim.x * 256)
        atomicAdd(&lh[dst[e] >> 7], 1);
    __syncthreads();
    for (int i = threadIdx.x; i < NBUCK; i += 256) {
        int v = lh[i];
        if (v) atomicAdd(&bcnt[i], v);
    }
}

// ---------------- scan 1024 -> exclusive bases + cursor copy ----------------
__global__ __launch_bounds__(256) void k_bscan(const int* __restrict__ in, int* __restrict__ out,
                                               int* __restrict__ cur) {
    __shared__ int sm[256];
    int t = threadIdx.x;
    int4 v = *(const int4*)&in[t * 4];
    int tsum = v.x + v.y + v.z + v.w;
    sm[t] = tsum;
    __syncthreads();
    for (int off = 1; off < 256; off <<= 1) {
        int val = sm[t];
        int add = (t >= off) ? sm[t - off] : 0;
        __syncthreads();
        sm[t] = val + add;
        __syncthreads();
    }
    int excl = sm[t] - tsum;
    int o0 = excl, o1 = excl + v.x, o2 = o1 + v.y, o3 = o2 + v.z;
    out[t * 4] = o0; out[t * 4 + 1] = o1; out[t * 4 + 2] = o2; out[t * 4 + 3] = o3;
    if (cur) { cur[t * 4] = o0; cur[t * 4 + 1] = o1; cur[t * 4 + 2] = o2; cur[t * 4 + 3] = o3; }
}

// ---------------- bin edges into per-bucket packed segments ----------------
__global__ __launch_bounds__(256) void k_bin(const int* __restrict__ src, const int* __restrict__ dst,
                                             int* __restrict__ bcur, unsigned int* __restrict__ pairs) {
    __shared__ int lhist[NBUCK];
    __shared__ int lbase[NBUCK];
    int t = threadIdx.x;
    for (int i = t; i < NBUCK; i += 256) lhist[i] = 0;
    __syncthreads();
    int base = blockIdx.x * EPB;
    int lim = min(base + EPB, N_EDGES);
    for (int e = base + t; e < lim; e += 256)
        atomicAdd(&lhist[dst[e] >> 7], 1);
    __syncthreads();
    for (int i = t; i < NBUCK; i += 256) {
        int h = lhist[i];
        lbase[i] = h ? atomicAdd(&bcur[i], h) : 0;
        lhist[i] = 0;
    }
    __syncthreads();
    for (int e = base + t; e < lim; e += 256) {
        int d = dst[e];
        int b = d >> 7;
        int r = atomicAdd(&lhist[b], 1);
        pairs[lbase[b] + r] = ((unsigned int)src[e] << 7) | ((unsigned int)d & 127u);
    }
}

// ---------------- per-bucket CSR fill + deg/offs/dinv ----------------
__global__ __launch_bounds__(256) void k_bfill(const unsigned int* __restrict__ pairs,
                                               const int* __restrict__ boffs,
                                               int* __restrict__ offs, int* __restrict__ deg,
                                               float* __restrict__ dinv, int* __restrict__ perm) {
    __shared__ int lcur[128];
    __shared__ int lsc[128];
    __shared__ int loff[128];
    int b = blockIdx.x;
    int t = threadIdx.x;
    if (t < 128) lcur[t] = 0;
    __syncthreads();
    int p0 = boffs[b];
    int p1 = (b == NBUCK - 1) ? N_EDGES : boffs[b + 1];
    for (int p = p0 + t; p < p1; p += 256)
        atomicAdd(&lcur[pairs[p] & 127u], 1);
    __syncthreads();
    if (t < 128) lsc[t] = lcur[t];
    __syncthreads();
    for (int off = 1; off < 128; off <<= 1) {
        int val = 0, add = 0;
        if (t < 128) { val = lsc[t]; add = (t >= off) ? lsc[t - off] : 0; }
        __syncthreads();
        if (t < 128) lsc[t] = val + add;
        __syncthreads();
    }
    if (t < 128) {
        int cnt = lcur[t];
        int excl = lsc[t] - cnt + p0;
        loff[t] = excl;
        int node = (b << 7) + t;
        if (node < N_NODES) {
            offs[node] = excl;
            deg[node] = cnt;
            dinv[node] = rsqrtf((float)(cnt + 1));
        }
        lcur[t] = 0;
    }
    __syncthreads();
    for (int p = p0 + t; p < p1; p += 256) {
        unsigned int e = pairs[p];
        int local = (int)(e & 127u);
        int r = atomicAdd(&lcur[local], 1);
        perm[loff[local] + r] = (int)(e >> 7);
    }
}

// ---------------- fold BN into per-channel A/B ----------------
__global__ void k_prep(const float* __restrict__ gamma, const float* __restrict__ beta,
                       const float* __restrict__ rmean, const float* __restrict__ rvar,
                       const float* __restrict__ b1, float* __restrict__ A1, float* __restrict__ B1) {
    int c = threadIdx.x;
    float a = gamma[c] * rsqrtf(rvar[c] + BN_EPS);
    A1[c] = a;
    B1[c] = (b1[c] - rmean[c]) * a + beta[c];
}

// ---------------- GEMM: int8 out with row-max quant; MODE 0 fp32 in, MODE 2 int8 in ----------------
template <int MODE>
__global__ __launch_bounds__(256) void k_gemm(const void* __restrict__ Xv, const float* __restrict__ xsc,
                                              const float* __restrict__ W, const float* __restrict__ dinvp,
                                              uint2* __restrict__ Yq, float* __restrict__ ospre, int nrows) {
    __shared__ float xsT[128 * 64];  // [k][r]
    int row0 = blockIdx.x * 64;
    int t = threadIdx.x;
    {
        int r = t >> 2, q = t & 3;
        int grow = row0 + r;
        bool ok = grow < nrows;
        if (MODE == 2) {
            float sc = ok ? xsc[grow] : 0.f;
            const uint2* srcp = (const uint2*)Xv + (size_t)grow * 16 + q * 4;
            #pragma unroll
            for (int i = 0; i < 4; ++i) {
                uint2 u = ok ? srcp[i] : make_uint2(0, 0);
                int a = (int)u.x, bb = (int)u.y;
                int c = q * 32 + i * 8;
                xsT[(c + 0) * 64 + r] = sc * (float)((a << 24) >> 24);
                xsT[(c + 1) * 64 + r] = sc * (float)((a << 16) >> 24);
                xsT[(c + 2) * 64 + r] = sc * (float)((a << 8) >> 24);
                xsT[(c + 3) * 64 + r] = sc * (float)(a >> 24);
                xsT[(c + 4) * 64 + r] = sc * (float)((bb << 24) >> 24);
                xsT[(c + 5) * 64 + r] = sc * (float)((bb << 16) >> 24);
                xsT[(c + 6) * 64 + r] = sc * (float)((bb << 8) >> 24);
                xsT[(c + 7) * 64 + r] = sc * (float)(bb >> 24);
            }
        } else {
            const float4* srcp = (const float4*)((const float*)Xv + (size_t)grow * CH + q * 32);
            #pragma unroll
            for (int i = 0; i < 8; ++i) {
                float4 v = ok ? srcp[i] : make_float4(0.f, 0.f, 0.f, 0.f);
                int c = q * 32 + i * 4;
                xsT[(c + 0) * 64 + r] = v.x;
                xsT[(c + 1) * 64 + r] = v.y;
                xsT[(c + 2) * 64 + r] = v.z;
                xsT[(c + 3) * 64 + r] = v.w;
            }
        }
    }
    __syncthreads();
    int tx = t & 15, ty = t >> 4;
    float acc[4][8];
    #pragma unroll
    for (int i = 0; i < 4; ++i)
        #pragma unroll
        for (int j = 0; j < 8; ++j) acc[i][j] = 0.f;

    const float4* xs4 = (const float4*)xsT;
    #pragma unroll 4
    for (int k = 0; k < 128; ++k) {
        float4 a = xs4[k * 16 + ty];
        float4 w0 = *(const float4*)&W[k * CH + tx * 8];
        float4 w1 = *(const float4*)&W[k * CH + tx * 8 + 4];
        float av[4] = {a.x, a.y, a.z, a.w};
        float wv[8] = {w0.x, w0.y, w0.z, w0.w, w1.x, w1.y, w1.z, w1.w};
        #pragma unroll
        for (int i = 0; i < 4; ++i)
            #pragma unroll
            for (int j = 0; j < 8; ++j) acc[i][j] += av[i] * wv[j];
    }
    #pragma unroll
    for (int i = 0; i < 4; ++i) {
        int grow = row0 + ty * 4 + i;
        float m = 0.f;
        #pragma unroll
        for (int j = 0; j < 8; ++j) m = fmaxf(m, fabsf(acc[i][j]));
        #pragma unroll
        for (int off = 1; off < 16; off <<= 1) m = fmaxf(m, __shfl_xor(m, off, 64));
        float inv = (m > 0.f) ? 127.0f / m : 0.f;
        if (grow < nrows) {
            uint2 pk;
            pk.x = packq(&acc[i][0], inv);
            pk.y = packq(&acc[i][4], inv);
            Yq[(size_t)grow * 16 + tx] = pk;
            if (tx == 0) ospre[grow] = (m * (1.0f / 127.0f)) * dinvp[grow];
        }
    }
}

// ---------------- SpMM gather: R8 shape (4 slots x 16 lanes, uint2) + 32-edge MLP stage ----------------
#define ACCI8(f, v)                                                                    \
    { int _a = (int)v.x, _b = (int)v.y;                                                \
      acc[0] += f * (float)((_a << 24) >> 24);                                         \
      acc[1] += f * (float)((_a << 16) >> 24);                                         \
      acc[2] += f * (float)((_a << 8) >> 24);                                          \
      acc[3] += f * (float)(_a >> 24);                                                 \
      acc[4] += f * (float)((_b << 24) >> 24);                                         \
      acc[5] += f * (float)((_b << 16) >> 24);                                         \
      acc[6] += f * (float)((_b << 8) >> 24);                                          \
      acc[7] += f * (float)(_b >> 24); }

#define SPMM_GATHER()                                                                  \
    int w = threadIdx.x >> 6;                                                          \
    int row = __builtin_amdgcn_readfirstlane(blockIdx.x * 4 + w);                      \
    int lane = threadIdx.x & 63;                                                       \
    int g = lane >> 4, c = lane & 15;                                                  \
    float di = dinv[row];                                                              \
    float acc[8];                                                                      \
    _Pragma("unroll") for (int i = 0; i < 8; ++i) acc[i] = 0.f;                        \
    int beg = offs[row], end = beg + deg[row];                                         \
    int j = beg + g;                                                                   \
    for (; j + 28 < end; j += 32) {                                                    \
        int s0 = perm[j],      s1 = perm[j + 4],  s2 = perm[j + 8],  s3 = perm[j + 12];\
        int s4 = perm[j + 16], s5 = perm[j + 20], s6 = perm[j + 24], s7 = perm[j + 28];\
        float f0 = spre[s0], f1 = spre[s1], f2 = spre[s2], f3 = spre[s3];              \
        float f4 = spre[s4], f5 = spre[s5], f6 = spre[s6], f7 = spre[s7];              \
        uint2 v0 = xq[(size_t)s0 * 16 + c];                                            \
        uint2 v1 = xq[(size_t)s1 * 16 + c];                                            \
        uint2 v2 = xq[(size_t)s2 * 16 + c];                                            \
        uint2 v3 = xq[(size_t)s3 * 16 + c];                                            \
        uint2 v4 = xq[(size_t)s4 * 16 + c];                                            \
        uint2 v5 = xq[(size_t)s5 * 16 + c];                                            \
        uint2 v6 = xq[(size_t)s6 * 16 + c];                                            \
        uint2 v7 = xq[(size_t)s7 * 16 + c];                                            \
        f0 *= di; f1 *= di; f2 *= di; f3 *= di;                                        \
        f4 *= di; f5 *= di; f6 *= di; f7 *= di;                                        \
        ACCI8(f0, v0) ACCI8(f1, v1) ACCI8(f2, v2) ACCI8(f3, v3)                        \
        ACCI8(f4, v4) ACCI8(f5, v5) ACCI8(f6, v6) ACCI8(f7, v7)                        \
    }                                                                                  \
    for (; j + 12 < end; j += 16) {                                                    \
        int s0 = perm[j], s1 = perm[j + 4], s2 = perm[j + 8], s3 = perm[j + 12];       \
        float f0 = spre[s0], f1 = spre[s1], f2 = spre[s2], f3 = spre[s3];              \
        uint2 v0 = xq[(size_t)s0 * 16 + c];                                            \
        uint2 v1 = xq[(size_t)s1 * 16 + c];                                            \
        uint2 v2 = xq[(size_t)s2 * 16 + c];                                            \
        uint2 v3 = xq[(size_t)s3 * 16 + c];                                            \
        f0 *= di; f1 *= di; f2 *= di; f3 *= di;                                        \
        ACCI8(f0, v0) ACCI8(f1, v1) ACCI8(f2, v2) ACCI8(f3, v3)                        \
    }                                                                                  \
    for (; j + 4 < end; j += 8) {                                                      \
        int s0 = perm[j], s1 = perm[j + 4];                                            \
        float f0 = di * spre[s0], f1 = di * spre[s1];                                  \
        uint2 v0 = xq[(size_t)s0 * 16 + c];                                            \
        uint2 v1 = xq[(size_t)s1 * 16 + c];                                            \
        ACCI8(f0, v0) ACCI8(f1, v1)                                                    \
    }                                                                                  \
    if (j < end) {                                                                     \
        int s = perm[j];                                                               \
        float f = di * spre[s];                                                        \
        uint2 v = xq[(size_t)s * 16 + c];                                              \
        ACCI8(f, v)                                                                    \
    }                                                                                  \
    _Pragma("unroll") for (int i = 0; i < 8; ++i) {                                    \
        acc[i] += __shfl_xor(acc[i], 16, 64);                                          \
        acc[i] += __shfl_xor(acc[i], 32, 64);                                          \
    }

// ---------------- SpMM layer 1: aggregate + folded BN/ReLU -> int8 + raw scale ----------------
__global__ __launch_bounds__(256) void k_spmm_bn_relu(
    const uint2* __restrict__ xq, const int* __restrict__ perm, const int* __restrict__ offs,
    const int* __restrict__ deg, const float* __restrict__ dinv, const float* __restrict__ spre,
    const float* __restrict__ A1, const float* __restrict__ B1,
    uint2* __restrict__ outq, float* __restrict__ osraw) {
    SPMM_GATHER()
    if (g == 0) {
        uint2 v = xq[(size_t)row * 16 + c];
        float fs = di * spre[row];
        ACCI8(fs, v)
        int ch = c * 8;
        float r[8];
        const float4* A4 = (const float4*)&A1[ch];
        const float4* B4 = (const float4*)&B1[ch];
        #pragma unroll
        for (int q = 0; q < 2; ++q) {
            float4 aa = A4[q], bb = B4[q];
            r[q * 4 + 0] = fmaxf(acc[q * 4 + 0] * aa.x + bb.x, 0.f);
            r[q * 4 + 1] = fmaxf(acc[q * 4 + 1] * aa.y + bb.y, 0.f);
            r[q * 4 + 2] = fmaxf(acc[q * 4 + 2] * aa.z + bb.z, 0.f);
            r[q * 4 + 3] = fmaxf(acc[q * 4 + 3] * aa.w + bb.w, 0.f);
        }
        float m = 0.f;
        #pragma unroll
        for (int i = 0; i < 8; ++i) m = fmaxf(m, r[i]);
        #pragma unroll
        for (int off = 1; off < 16; off <<= 1) m = fmaxf(m, __shfl_xor(m, off, 64));
        float inv = (m > 0.f) ? 127.0f / m : 0.f;
        uint2 pk;
        pk.x = packq(&r[0], inv);
        pk.y = packq(&r[4], inv);
        outq[(size_t)row * 16 + c] = pk;
        if (c == 0) osraw[row] = m * (1.0f / 127.0f);
    }
}

// ---------------- SpMM layer 2: aggregate + bias + pooled-sum (block-reduced atomics) ----------------
__global__ __launch_bounds__(256) void k_spmm_pool(
    const uint2* __restrict__ xq, const int* __restrict__ perm, const int* __restrict__ offs,
    const int* __restrict__ deg, const float* __restrict__ dinv, const float* __restrict__ spre,
    const float* __restrict__ bias, const int* __restrict__ batch,
    float* __restrict__ psum, int* __restrict__ pcnt) {
    __shared__ float red[4][128];
    __shared__ int gid[4];
    SPMM_GATHER()
    if (g == 0) {
        uint2 v = xq[(size_t)row * 16 + c];
        float fs = di * spre[row];
        ACCI8(fs, v)
        int ch = c * 8;
        #pragma unroll
        for (int i = 0; i < 8; ++i) red[w][ch + i] = acc[i] + bias[ch + i];
    }
    if (lane == 0) gid[w] = batch[row];
    __syncthreads();
    bool same = (gid[0] == gid[1]) && (gid[1] == gid[2]) && (gid[2] == gid[3]);
    int c0 = lane * 2;
    if (same) {
        if (w == 0) {
            float sx = red[0][c0] + red[1][c0] + red[2][c0] + red[3][c0];
            float sy = red[0][c0 + 1] + red[1][c0 + 1] + red[2][c0 + 1] + red[3][c0 + 1];
            unsafeAtomicAdd(&psum[gid[0] * CH + c0], sx);
            unsafeAtomicAdd(&psum[gid[0] * CH + c0 + 1], sy);
            if (lane == 0) atomicAdd(&pcnt[gid[0]], 4);
        }
    } else {
        unsafeAtomicAdd(&psum[gid[w] * CH + c0], red[w][c0]);
        unsafeAtomicAdd(&psum[gid[w] * CH + c0 + 1], red[w][c0 + 1]);
        if (lane == 0) atomicAdd(&pcnt[gid[w]], 1);
    }
}

// ---------------- head ----------------
__global__ __launch_bounds__(128) void k_head(const float* __restrict__ psum, const int* __restrict__ pcnt,
                                              const float* __restrict__ fw1, const float* __restrict__ fb1,
                                              const float* __restrict__ cw, const float* __restrict__ cb,
                                              float* __restrict__ out) {
    __shared__ float fws[128 * 64];
    for (int i = threadIdx.x; i < 128 * 64; i += 128) fws[i] = fw1[i];
    __syncthreads();
    int g = threadIdx.x;
    float z[64];
    #pragma unroll
    for (int j = 0; j < 64; ++j) z[j] = fb1[j];
    float cnt = fmaxf((float)pcnt[g], 1.f);
    float inv = 1.f / cnt;
    for (int c = 0; c < 128; ++c) {
        float p = psum[g * CH + c] * inv;
        #pragma unroll
        for (int j = 0; j < 64; ++j) z[j] += p * fws[c * 64 + j];
    }
    float o0 = cb[0], o1 = cb[1];
    #pragma unroll
    for (int j = 0; j < 64; ++j) {
        float zz = fmaxf(z[j], 0.f);
        o0 += zz * cw[j * 2];
        o1 += zz * cw[j * 2 + 1];
    }
    out[g * 2] = o0;
    out[g * 2 + 1] = o1;
}

extern "C" void kernel_launch(void* const* d_in, const int* in_sizes, int n_in,
                              void* d_out, int out_size, void* d_ws, size_t ws_size,
                              hipStream_t stream) {
    const float* x     = (const float*)d_in[0];
    const int*   ei    = (const int*)d_in[1];
    const int*   batch = (const int*)d_in[2];
    const float* W1    = (const float*)d_in[3];
    const float* b1    = (const float*)d_in[4];
    const float* gamma = (const float*)d_in[5];
    const float* beta  = (const float*)d_in[6];
    const float* rmean = (const float*)d_in[7];
    const float* rvar  = (const float*)d_in[8];
    const float* W2    = (const float*)d_in[9];
    const float* b2    = (const float*)d_in[10];
    const float* fw1   = (const float*)d_in[11];
    const float* fb1   = (const float*)d_in[12];
    const float* cw    = (const float*)d_in[13];
    const float* cb    = (const float*)d_in[14];
    const int* srcp = ei;
    const int* dstp = ei + N_EDGES;

    char* w = (char*)d_ws;
    // zeroed region first
    int*   bcnt  = (int*)w;   w += 4096;
    float* psum  = (float*)w; w += 65536;
    int*   pcnt  = (int*)w;   w += 512;
    size_t zbytes = 4096 + 65536 + 512;
    // non-zeroed
    int*   deg   = (int*)w;   w += 400000;
    int*   offs  = (int*)w;   w += 400000;
    float* dinv  = (float*)w; w += 400000;
    float* spreA = (float*)w; w += 400000;
    float* srawB = (float*)w; w += 400000;
    float* spreC = (float*)w; w += 400000;
    float* A1    = (float*)w; w += 512;
    float* B1    = (float*)w; w += 512;
    int*   boffs = (int*)w;   w += 4096;
    int*   bcur  = (int*)w;   w += 4096;
    unsigned int* pairs = (unsigned int*)w; w += 12800000;
    int*   perm  = (int*)w;   w += 12800000;
    uint2* bufA  = (uint2*)w; w += 12800000;  // int8 [100k,128]
    uint2* bufB  = (uint2*)w; w += 12800000;  // int8 [100k,128]
    uint2* bufC  = (uint2*)w; w += 12800000;  // int8 [100k,128]

    hipMemsetAsync(d_ws, 0, zbytes, stream);
    k_bhist<<<200, 256, 0, stream>>>(dstp, bcnt);
    k_bscan<<<1, 256, 0, stream>>>(bcnt, boffs, bcur);
    k_bin<<<(N_EDGES + EPB - 1) / EPB, 256, 0, stream>>>(srcp, dstp, bcur, pairs);
    k_bfill<<<NBUCK, 256, 0, stream>>>(pairs, boffs, offs, deg, dinv, perm);
    k_prep<<<1, 128, 0, stream>>>(gamma, beta, rmean, rvar, b1, A1, B1);
    k_gemm<0><<<1563, 256, 0, stream>>>(x, nullptr, W1, dinv, bufA, spreA, N_NODES);
    k_spmm_bn_relu<<<25000, 256, 0, stream>>>(bufA, perm, offs, deg, dinv, spreA,
                                              A1, B1, bufB, srawB);
    k_gemm<2><<<1563, 256, 0, stream>>>(bufB, srawB, W2, dinv, bufC, spreC, N_NODES);
    k_spmm_pool<<<25000, 256, 0, stream>>>(bufC, perm, offs, deg, dinv, spreC, b2, batch, psum, pcnt);
    k_head<<<1, 128, 0, stream>>>(psum, pcnt, fw1, fb1, cw, cb, (float*)d_out);
}

// Round 11
// 603.398 us; speedup vs baseline: 1.1488x; 1.0693x over previous
//
#include <hip/hip_runtime.h>
#include <hip/hip_bf16.h>

#define N_NODES 100000
#define N_EDGES 3200000
#define CH 128
#define NG 128
#define BN_EPS 1e-5f
#define NBUCK 1024   // bucket = dst >> 7 (128 nodes per bucket)
#define EPB 16384    // edges per k_bin block

using i32x4 = __attribute__((ext_vector_type(4))) int;

__device__ __forceinline__ unsigned int packq(const float* v, float inv) {
    int q0 = __float2int_rn(v[0] * inv), q1 = __float2int_rn(v[1] * inv);
    int q2 = __float2int_rn(v[2] * inv), q3 = __float2int_rn(v[3] * inv);
    return (unsigned int)(q0 & 255) | ((unsigned int)(q1 & 255) << 8) |
           ((unsigned int)(q2 & 255) << 16) | ((unsigned int)(q3 & 255) << 24);
}

// ---------------- quantize x rows to int8 + per-row scale ----------------
__global__ __launch_bounds__(256) void k_quantx(const float* __restrict__ x,
                                                unsigned char* __restrict__ Xq,
                                                float* __restrict__ xs) {
    int t = threadIdx.x;
    int row = blockIdx.x * 16 + (t >> 4);
    int seg = t & 15;
    const float4* p = (const float4*)&x[(size_t)row * CH + seg * 8];
    float4 a = p[0], b = p[1];
    float v[8] = {a.x, a.y, a.z, a.w, b.x, b.y, b.z, b.w};
    float m = 0.f;
    #pragma unroll
    for (int i = 0; i < 8; ++i) m = fmaxf(m, fabsf(v[i]));
    m = fmaxf(m, __shfl_xor(m, 1, 64));
    m = fmaxf(m, __shfl_xor(m, 2, 64));
    m = fmaxf(m, __shfl_xor(m, 4, 64));
    m = fmaxf(m, __shfl_xor(m, 8, 64));
    float inv = (m > 0.f) ? 127.0f / m : 0.f;
    uint2 pk;
    pk.x = packq(&v[0], inv);
    pk.y = packq(&v[4], inv);
    *(uint2*)&Xq[(size_t)row * CH + seg * 8] = pk;
    if (seg == 0) xs[row] = m * (1.0f / 127.0f);
}

// ---------------- quantize W1/W2 per column (transposed) + BN fold ----------------
__global__ __launch_bounds__(256) void k_prepW(
    const float* __restrict__ W1, const float* __restrict__ W2,
    const float* __restrict__ gamma, const float* __restrict__ beta,
    const float* __restrict__ rmean, const float* __restrict__ rvar, const float* __restrict__ b1,
    unsigned char* __restrict__ Wq1T, float* __restrict__ wcs1,
    unsigned char* __restrict__ Wq2T, float* __restrict__ wcs2,
    float* __restrict__ A1, float* __restrict__ B1) {
    int t = threadIdx.x;
    const float* W = (t < 128) ? W1 : W2;
    unsigned char* WT = (t < 128) ? Wq1T : Wq2T;
    float* wcs = (t < 128) ? wcs1 : wcs2;
    int c = t & 127;
    float m = 0.f;
    for (int k = 0; k < 128; ++k) m = fmaxf(m, fabsf(W[k * CH + c]));
    float inv = (m > 0.f) ? 127.0f / m : 0.f;
    for (int k = 0; k < 128; ++k) {
        int q = __float2int_rn(W[k * CH + c] * inv);
        WT[c * CH + k] = (unsigned char)(q & 255);
    }
    wcs[c] = m * (1.0f / 127.0f);
    if (t < 128) {
        float a = gamma[c] * rsqrtf(rvar[c] + BN_EPS);
        A1[c] = a;
        B1[c] = (b1[c] - rmean[c]) * a + beta[c];
    }
}

// ---------------- bucket histogram ----------------
__global__ __launch_bounds__(256) void k_bhist(const int* __restrict__ dst, int* __restrict__ bcnt) {
    __shared__ int lh[NBUCK];
    for (int i = threadIdx.x; i < NBUCK; i += 256) lh[i] = 0;
    __syncthreads();
    for (int e = blockIdx.x * 256 + threadIdx.x; e < N_EDGES; e += gridDim.x * 256)
        atomicAdd(&lh[dst[e] >> 7], 1);
    __syncthreads();
    for (int i = threadIdx.x; i < NBUCK; i += 256) {
        int v = lh[i];
        if (v) atomicAdd(&bcnt[i], v);
    }
}

// ---------------- scan 1024 -> exclusive bases + cursor copy ----------------
__global__ __launch_bounds__(256) void k_bscan(const int* __restrict__ in, int* __restrict__ out,
                                               int* __restrict__ cur) {
    __shared__ int sm[256];
    int t = threadIdx.x;
    int4 v = *(const int4*)&in[t * 4];
    int tsum = v.x + v.y + v.z + v.w;
    sm[t] = tsum;
    __syncthreads();
    for (int off = 1; off < 256; off <<= 1) {
        int val = sm[t];
        int add = (t >= off) ? sm[t - off] : 0;
        __syncthreads();
        sm[t] = val + add;
        __syncthreads();
    }
    int excl = sm[t] - tsum;
    int o0 = excl, o1 = excl + v.x, o2 = o1 + v.y, o3 = o2 + v.z;
    out[t * 4] = o0; out[t * 4 + 1] = o1; out[t * 4 + 2] = o2; out[t * 4 + 3] = o3;
    if (cur) { cur[t * 4] = o0; cur[t * 4 + 1] = o1; cur[t * 4 + 2] = o2; cur[t * 4 + 3] = o3; }
}

// ---------------- bin edges into per-bucket packed segments ----------------
__global__ __launch_bounds__(256) void k_bin(const int* __restrict__ src, const int* __restrict__ dst,
                                             int* __restrict__ bcur, unsigned int* __restrict__ pairs) {
    __shared__ int lhist[NBUCK];
    __shared__ int lbase[NBUCK];
    int t = threadIdx.x;
    for (int i = t; i < NBUCK; i += 256) lhist[i] = 0;
    __syncthreads();
    int base = blockIdx.x * EPB;
    int lim = min(base + EPB, N_EDGES);
    for (int e = base + t; e < lim; e += 256)
        atomicAdd(&lhist[dst[e] >> 7], 1);
    __syncthreads();
    for (int i = t; i < NBUCK; i += 256) {
        int h = lhist[i];
        lbase[i] = h ? atomicAdd(&bcur[i], h) : 0;
        lhist[i] = 0;
    }
    __syncthreads();
    for (int e = base + t; e < lim; e += 256) {
        int d = dst[e];
        int b = d >> 7;
        int r = atomicAdd(&lhist[b], 1);
        pairs[lbase[b] + r] = ((unsigned int)src[e] << 7) | ((unsigned int)d & 127u);
    }
}

// ---------------- per-bucket CSR fill + deg/offs/dinv ----------------
__global__ __launch_bounds__(256) void k_bfill(const unsigned int* __restrict__ pairs,
                                               const int* __restrict__ boffs,
                                               int* __restrict__ offs, int* __restrict__ deg,
                                               float* __restrict__ dinv, int* __restrict__ perm) {
    __shared__ int lcur[128];
    __shared__ int lsc[128];
    __shared__ int loff[128];
    int b = blockIdx.x;
    int t = threadIdx.x;
    if (t < 128) lcur[t] = 0;
    __syncthreads();
    int p0 = boffs[b];
    int p1 = (b == NBUCK - 1) ? N_EDGES : boffs[b + 1];
    for (int p = p0 + t; p < p1; p += 256)
        atomicAdd(&lcur[pairs[p] & 127u], 1);
    __syncthreads();
    if (t < 128) lsc[t] = lcur[t];
    __syncthreads();
    for (int off = 1; off < 128; off <<= 1) {
        int val = 0, add = 0;
        if (t < 128) { val = lsc[t]; add = (t >= off) ? lsc[t - off] : 0; }
        __syncthreads();
        if (t < 128) lsc[t] = val + add;
        __syncthreads();
    }
    if (t < 128) {
        int cnt = lcur[t];
        int excl = lsc[t] - cnt + p0;
        loff[t] = excl;
        int node = (b << 7) + t;
        if (node < N_NODES) {
            offs[node] = excl;
            deg[node] = cnt;
            dinv[node] = rsqrtf((float)(cnt + 1));
        }
        lcur[t] = 0;
    }
    __syncthreads();
    for (int p = p0 + t; p < p1; p += 256) {
        unsigned int e = pairs[p];
        int local = (int)(e & 127u);
        int r = atomicAdd(&lcur[local], 1);
        perm[loff[local] + r] = (int)(e >> 7);
    }
}

// ---------------- MFMA int8 GEMM: Y_int8[N,128] = quant(Xq*xs @ WqT*wcs), + spre ----------------
// A frag: lane m=lane&15, k = quad*16+[0..15];  B frag (from WT[n][k]): n=lane&15, same k.
// C/D: col=lane&15 (within tile), row=quad*4+reg.
__global__ __launch_bounds__(256) void k_gemm_mfma(
    const unsigned char* __restrict__ Xq, const float* __restrict__ xs,
    const unsigned char* __restrict__ WT, const float* __restrict__ wcs,
    const float* __restrict__ dinvp, unsigned char* __restrict__ Yq, float* __restrict__ ospre) {
    __shared__ float ep[4][16][132];
    int t = threadIdx.x;
    int w = t >> 6;
    int lane = t & 63;
    int quad = lane >> 4, l16 = lane & 15;
    int row0 = blockIdx.x * 64 + w * 16;

    // A fragments (2 k-steps), clamp OOB rows
    int arow = row0 + l16;
    if (arow >= N_NODES) arow = N_NODES - 1;
    i32x4 a0 = *(const i32x4*)&Xq[(size_t)arow * CH + quad * 16];
    i32x4 a1 = *(const i32x4*)&Xq[(size_t)arow * CH + 64 + quad * 16];

    i32x4 acc[8];
    #pragma unroll
    for (int i = 0; i < 8; ++i) acc[i] = (i32x4){0, 0, 0, 0};

    #pragma unroll
    for (int tt = 0; tt < 8; ++tt) {
        int n = tt * 16 + l16;
        i32x4 b0 = *(const i32x4*)&WT[(size_t)n * CH + quad * 16];
        i32x4 b1 = *(const i32x4*)&WT[(size_t)n * CH + 64 + quad * 16];
        acc[tt] = __builtin_amdgcn_mfma_i32_16x16x64_i8(a0, b0, acc[tt], 0, 0, 0);
        acc[tt] = __builtin_amdgcn_mfma_i32_16x16x64_i8(a1, b1, acc[tt], 0, 0, 0);
    }

    // scale + stage to LDS
    float xsr[4];
    #pragma unroll
    for (int r = 0; r < 4; ++r) {
        int rr = row0 + quad * 4 + r;
        xsr[r] = xs[(rr < N_NODES) ? rr : (N_NODES - 1)];
    }
    #pragma unroll
    for (int tt = 0; tt < 8; ++tt) {
        float wc = wcs[tt * 16 + l16];
        #pragma unroll
        for (int r = 0; r < 4; ++r)
            ep[w][quad * 4 + r][tt * 16 + l16] = (float)acc[tt][r] * xsr[r] * wc;
    }
    __syncthreads();

    // requantize rows: 4 lanes per row, 32 ch each
    int rl = lane >> 2, part = lane & 3;
    int grow = row0 + rl;
    float v[32];
    float m = 0.f;
    #pragma unroll
    for (int i = 0; i < 32; ++i) {
        v[i] = ep[w][rl][part * 32 + i];
        m = fmaxf(m, fabsf(v[i]));
    }
    m = fmaxf(m, __shfl_xor(m, 1, 64));
    m = fmaxf(m, __shfl_xor(m, 2, 64));
    if (grow < N_NODES) {
        float inv = (m > 0.f) ? 127.0f / m : 0.f;
        unsigned int o[8];
        #pragma unroll
        for (int q = 0; q < 8; ++q) o[q] = packq(&v[q * 4], inv);
        uint4* dst0 = (uint4*)&Yq[(size_t)grow * CH + part * 32];
        dst0[0] = make_uint4(o[0], o[1], o[2], o[3]);
        dst0[1] = make_uint4(o[4], o[5], o[6], o[7]);
        if (part == 0) ospre[grow] = (m * (1.0f / 127.0f)) * dinvp[grow];
    }
}

// ---------------- SpMM gather: 4 slots x 16 lanes, uint2, deep unroll ----------------
#define ACCI8(f, v)                                                                    \
    { int _a = (int)v.x, _b = (int)v.y;                                                \
      acc[0] += f * (float)((_a << 24) >> 24);                                         \
      acc[1] += f * (float)((_a << 16) >> 24);                                         \
      acc[2] += f * (float)((_a << 8) >> 24);                                          \
      acc[3] += f * (float)(_a >> 24);                                                 \
      acc[4] += f * (float)((_b << 24) >> 24);                                         \
      acc[5] += f * (float)((_b << 16) >> 24);                                         \
      acc[6] += f * (float)((_b << 8) >> 24);                                          \
      acc[7] += f * (float)(_b >> 24); }

#define SPMM_GATHER()                                                                  \
    int w = threadIdx.x >> 6;                                                          \
    int row = __builtin_amdgcn_readfirstlane(blockIdx.x * 4 + w);                      \
    int lane = threadIdx.x & 63;                                                       \
    int g = lane >> 4, c = lane & 15;                                                  \
    float di = dinv[row];                                                              \
    float acc[8];                                                                      \
    _Pragma("unroll") for (int i = 0; i < 8; ++i) acc[i] = 0.f;                        \
    int beg = offs[row], end = beg + deg[row];                                         \
    int j = beg + g;                                                                   \
    for (; j + 28 < end; j += 32) {                                                    \
        int s0 = perm[j],      s1 = perm[j + 4],  s2 = perm[j + 8],  s3 = perm[j + 12];\
        int s4 = perm[j + 16], s5 = perm[j + 20], s6 = perm[j + 24], s7 = perm[j + 28];\
        float f0 = spre[s0], f1 = spre[s1], f2 = spre[s2], f3 = spre[s3];              \
        float f4 = spre[s4], f5 = spre[s5], f6 = spre[s6], f7 = spre[s7];              \
        uint2 v0 = xq[(size_t)s0 * 16 + c];                                            \
        uint2 v1 = xq[(size_t)s1 * 16 + c];                                            \
        uint2 v2 = xq[(size_t)s2 * 16 + c];                                            \
        uint2 v3 = xq[(size_t)s3 * 16 + c];                                            \
        uint2 v4 = xq[(size_t)s4 * 16 + c];                                            \
        uint2 v5 = xq[(size_t)s5 * 16 + c];                                            \
        uint2 v6 = xq[(size_t)s6 * 16 + c];                                            \
        uint2 v7 = xq[(size_t)s7 * 16 + c];                                            \
        f0 *= di; f1 *= di; f2 *= di; f3 *= di;                                        \
        f4 *= di; f5 *= di; f6 *= di; f7 *= di;                                        \
        ACCI8(f0, v0) ACCI8(f1, v1) ACCI8(f2, v2) ACCI8(f3, v3)                        \
        ACCI8(f4, v4) ACCI8(f5, v5) ACCI8(f6, v6) ACCI8(f7, v7)                        \
    }                                                                                  \
    for (; j + 12 < end; j += 16) {                                                    \
        int s0 = perm[j], s1 = perm[j + 4], s2 = perm[j + 8], s3 = perm[j + 12];       \
        float f0 = spre[s0], f1 = spre[s1], f2 = spre[s2], f3 = spre[s3];              \
        uint2 v0 = xq[(size_t)s0 * 16 + c];                                            \
        uint2 v1 = xq[(size_t)s1 * 16 + c];                                            \
        uint2 v2 = xq[(size_t)s2 * 16 + c];                                            \
        uint2 v3 = xq[(size_t)s3 * 16 + c];                                            \
        f0 *= di; f1 *= di; f2 *= di; f3 *= di;                                        \
        ACCI8(f0, v0) ACCI8(f1, v1) ACCI8(f2, v2) ACCI8(f3, v3)                        \
    }                                                                                  \
    for (; j + 4 < end; j += 8) {                                                      \
        int s0 = perm[j], s1 = perm[j + 4];                                            \
        float f0 = di * spre[s0], f1 = di * spre[s1];                                  \
        uint2 v0 = xq[(size_t)s0 * 16 + c];                                            \
        uint2 v1 = xq[(size_t)s1 * 16 + c];                                            \
        ACCI8(f0, v0) ACCI8(f1, v1)                                                    \
    }                                                                                  \
    if (j < end) {                                                                     \
        int s = perm[j];                                                               \
        float f = di * spre[s];                                                        \
        uint2 v = xq[(size_t)s * 16 + c];                                              \
        ACCI8(f, v)                                                                    \
    }                                                                                  \
    _Pragma("unroll") for (int i = 0; i < 8; ++i) {                                    \
        acc[i] += __shfl_xor(acc[i], 16, 64);                                          \
        acc[i] += __shfl_xor(acc[i], 32, 64);                                          \
    }

// ---------------- SpMM layer 1: aggregate + folded BN/ReLU -> int8 + raw scale ----------------
__global__ __launch_bounds__(256) void k_spmm_bn_relu(
    const uint2* __restrict__ xq, const int* __restrict__ perm, const int* __restrict__ offs,
    const int* __restrict__ deg, const float* __restrict__ dinv, const float* __restrict__ spre,
    const float* __restrict__ A1, const float* __restrict__ B1,
    uint2* __restrict__ outq, float* __restrict__ osraw) {
    SPMM_GATHER()
    if (g == 0) {
        uint2 v = xq[(size_t)row * 16 + c];
        float fs = di * spre[row];
        ACCI8(fs, v)
        int ch = c * 8;
        float r[8];
        const float4* A4 = (const float4*)&A1[ch];
        const float4* B4 = (const float4*)&B1[ch];
        #pragma unroll
        for (int q = 0; q < 2; ++q) {
            float4 aa = A4[q], bb = B4[q];
            r[q * 4 + 0] = fmaxf(acc[q * 4 + 0] * aa.x + bb.x, 0.f);
            r[q * 4 + 1] = fmaxf(acc[q * 4 + 1] * aa.y + bb.y, 0.f);
            r[q * 4 + 2] = fmaxf(acc[q * 4 + 2] * aa.z + bb.z, 0.f);
            r[q * 4 + 3] = fmaxf(acc[q * 4 + 3] * aa.w + bb.w, 0.f);
        }
        float m = 0.f;
        #pragma unroll
        for (int i = 0; i < 8; ++i) m = fmaxf(m, r[i]);
        #pragma unroll
        for (int off = 1; off < 16; off <<= 1) m = fmaxf(m, __shfl_xor(m, off, 64));
        float inv = (m > 0.f) ? 127.0f / m : 0.f;
        uint2 pk;
        pk.x = packq(&r[0], inv);
        pk.y = packq(&r[4], inv);
        outq[(size_t)row * 16 + c] = pk;
        if (c == 0) osraw[row] = m * (1.0f / 127.0f);
    }
}

// ---------------- SpMM layer 2: aggregate + bias + pooled-sum ----------------
__global__ __launch_bounds__(256) void k_spmm_pool(
    const uint2* __restrict__ xq, const int* __restrict__ perm, const int* __restrict__ offs,
    const int* __restrict__ deg, const float* __restrict__ dinv, const float* __restrict__ spre,
    const float* __restrict__ bias, const int* __restrict__ batch,
    float* __restrict__ psum, int* __restrict__ pcnt) {
    __shared__ float red[4][128];
    __shared__ int gid[4];
    SPMM_GATHER()
    if (g == 0) {
        uint2 v = xq[(size_t)row * 16 + c];
        float fs = di * spre[row];
        ACCI8(fs, v)
        int ch = c * 8;
        #pragma unroll
        for (int i = 0; i < 8; ++i) red[w][ch + i] = acc[i] + bias[ch + i];
    }
    if (lane == 0) gid[w] = batch[row];
    __syncthreads();
    bool same = (gid[0] == gid[1]) && (gid[1] == gid[2]) && (gid[2] == gid[3]);
    int c0 = lane * 2;
    if (same) {
        if (w == 0) {
            float sx = red[0][c0] + red[1][c0] + red[2][c0] + red[3][c0];
            float sy = red[0][c0 + 1] + red[1][c0 + 1] + red[2][c0 + 1] + red[3][c0 + 1];
            unsafeAtomicAdd(&psum[gid[0] * CH + c0], sx);
            unsafeAtomicAdd(&psum[gid[0] * CH + c0 + 1], sy);
            if (lane == 0) atomicAdd(&pcnt[gid[0]], 4);
        }
    } else {
        unsafeAtomicAdd(&psum[gid[w] * CH + c0], red[w][c0]);
        unsafeAtomicAdd(&psum[gid[w] * CH + c0 + 1], red[w][c0 + 1]);
        if (lane == 0) atomicAdd(&pcnt[gid[w]], 1);
    }
}

// ---------------- head ----------------
__global__ __launch_bounds__(128) void k_head(const float* __restrict__ psum, const int* __restrict__ pcnt,
                                              const float* __restrict__ fw1, const float* __restrict__ fb1,
                                              const float* __restrict__ cw, const float* __restrict__ cb,
                                              float* __restrict__ out) {
    __shared__ float fws[128 * 64];
    for (int i = threadIdx.x; i < 128 * 64; i += 128) fws[i] = fw1[i];
    __syncthreads();
    int g = threadIdx.x;
    float z[64];
    #pragma unroll
    for (int j = 0; j < 64; ++j) z[j] = fb1[j];
    float cnt = fmaxf((float)pcnt[g], 1.f);
    float inv = 1.f / cnt;
    for (int c = 0; c < 128; ++c) {
        float p = psum[g * CH + c] * inv;
        #pragma unroll
        for (int j = 0; j < 64; ++j) z[j] += p * fws[c * 64 + j];
    }
    float o0 = cb[0], o1 = cb[1];
    #pragma unroll
    for (int j = 0; j < 64; ++j) {
        float zz = fmaxf(z[j], 0.f);
        o0 += zz * cw[j * 2];
        o1 += zz * cw[j * 2 + 1];
    }
    out[g * 2] = o0;
    out[g * 2 + 1] = o1;
}

extern "C" void kernel_launch(void* const* d_in, const int* in_sizes, int n_in,
                              void* d_out, int out_size, void* d_ws, size_t ws_size,
                              hipStream_t stream) {
    const float* x     = (const float*)d_in[0];
    const int*   ei    = (const int*)d_in[1];
    const int*   batch = (const int*)d_in[2];
    const float* W1    = (const float*)d_in[3];
    const float* b1    = (const float*)d_in[4];
    const float* gamma = (const float*)d_in[5];
    const float* beta  = (const float*)d_in[6];
    const float* rmean = (const float*)d_in[7];
    const float* rvar  = (const float*)d_in[8];
    const float* W2    = (const float*)d_in[9];
    const float* b2    = (const float*)d_in[10];
    const float* fw1   = (const float*)d_in[11];
    const float* fb1   = (const float*)d_in[12];
    const float* cw    = (const float*)d_in[13];
    const float* cb    = (const float*)d_in[14];
    const int* srcp = ei;
    const int* dstp = ei + N_EDGES;

    char* w = (char*)d_ws;
    // zeroed region first
    int*   bcnt  = (int*)w;   w += 4096;
    float* psum  = (float*)w; w += 65536;
    int*   pcnt  = (int*)w;   w += 512;
    size_t zbytes = 4096 + 65536 + 512;
    // non-zeroed
    int*   deg   = (int*)w;   w += 400000;
    int*   offs  = (int*)w;   w += 400000;
    float* dinv  = (float*)w; w += 400000;
    float* xsA   = (float*)w; w += 400000;
    float* spreA = (float*)w; w += 400000;
    float* srawB = (float*)w; w += 400000;
    float* spreC = (float*)w; w += 400000;
    float* A1    = (float*)w; w += 512;
    float* B1    = (float*)w; w += 512;
    float* wcs1  = (float*)w; w += 512;
    float* wcs2  = (float*)w; w += 512;
    unsigned char* Wq1T = (unsigned char*)w; w += 16384;
    unsigned char* Wq2T = (unsigned char*)w; w += 16384;
    int*   boffs = (int*)w;   w += 4096;
    int*   bcur  = (int*)w;   w += 4096;
    unsigned int* pairs = (unsigned int*)w; w += 12800000;
    int*   perm  = (int*)w;   w += 12800000;
    unsigned char* Xq   = (unsigned char*)w; w += 12800000;  // int8 [100k,128]
    unsigned char* bufA = (unsigned char*)w; w += 12800000;
    unsigned char* bufB = (unsigned char*)w; w += 12800000;
    unsigned char* bufC = (unsigned char*)w; w += 12800000;

    hipMemsetAsync(d_ws, 0, zbytes, stream);
    k_quantx<<<6250, 256, 0, stream>>>(x, Xq, xsA);
    k_bhist<<<200, 256, 0, stream>>>(dstp, bcnt);
    k_bscan<<<1, 256, 0, stream>>>(bcnt, boffs, bcur);
    k_bin<<<(N_EDGES + EPB - 1) / EPB, 256, 0, stream>>>(srcp, dstp, bcur, pairs);
    k_bfill<<<NBUCK, 256, 0, stream>>>(pairs, boffs, offs, deg, dinv, perm);
    k_prepW<<<1, 256, 0, stream>>>(W1, W2, gamma, beta, rmean, rvar, b1,
                                   Wq1T, wcs1, Wq2T, wcs2, A1, B1);
    k_gemm_mfma<<<1563, 256, 0, stream>>>(Xq, xsA, Wq1T, wcs1, dinv, bufA, spreA);
    k_spmm_bn_relu<<<25000, 256, 0, stream>>>((const uint2*)bufA, perm, offs, deg, dinv, spreA,
                                              A1, B1, (uint2*)bufB, srawB);
    k_gemm_mfma<<<1563, 256, 0, stream>>>(bufB, srawB, Wq2T, wcs2, dinv, bufC, spreC);
    k_spmm_pool<<<25000, 256, 0, stream>>>((const uint2*)bufC, perm, offs, deg, dinv, spreC,
                                           b2, batch, psum, pcnt);
    k_head<<<1, 128, 0, stream>>>(psum, pcnt, fw1, fb1, cw, cb, (float*)d_out);
}